// Round 6
// baseline (309.845 us; speedup 1.0000x reference)
//
#include <hip/hip_runtime.h>
#include <hip/hip_bf16.h>
#include <stdint.h>

// Problem constants (B,C,H,W)=(16,256,64,64), HEADS=8, BS=8, HALO=3
// Inputs f32; MFMA math bf16, f32 accumulate; output f32.
#define HEADS 8
#define WIN 14
#define NPOS 196          // WIN*WIN
#define NPAD 224          // padded key count = 7*32
#define NB 16
#define NC 256
#define NH 64
#define NW 64
#define NP 4096           // NH*NW
#define NKV 512           // kv channels (fallback layout)
#define NOC 768           // q(256) + kv(512) channels

typedef __bf16 bf16_t;
typedef bf16_t bf16x8 __attribute__((ext_vector_type(8)));
typedef float f32x4 __attribute__((ext_vector_type(4)));

union Frag {
  uint4 u4;
  bf16x8 b8;
  ushort us[8];
};

__device__ __forceinline__ ushort f2bf(float f) {
  bf16_t h = (bf16_t)f;
  return __builtin_bit_cast(ushort, h);
}
__device__ __forceinline__ float bf2f(ushort u) {
  uint32_t t = ((uint32_t)u) << 16;
  return __builtin_bit_cast(float, t);
}
__device__ __forceinline__ bf16x8 load_bf8(const float* __restrict__ p) {
  float4 a = *reinterpret_cast<const float4*>(p);
  float4 b = *reinterpret_cast<const float4*>(p + 4);
  bf16x8 r;
  r[0] = (bf16_t)a.x; r[1] = (bf16_t)a.y; r[2] = (bf16_t)a.z; r[3] = (bf16_t)a.w;
  r[4] = (bf16_t)b.x; r[5] = (bf16_t)b.y; r[6] = (bf16_t)b.z; r[7] = (bf16_t)b.w;
  return r;
}
__device__ __forceinline__ bf16x8 load_bf8s(const float* __restrict__ p, float s) {
  float4 a = *reinterpret_cast<const float4*>(p);
  float4 b = *reinterpret_cast<const float4*>(p + 4);
  bf16x8 r;
  r[0] = (bf16_t)(a.x * s); r[1] = (bf16_t)(a.y * s); r[2] = (bf16_t)(a.z * s); r[3] = (bf16_t)(a.w * s);
  r[4] = (bf16_t)(b.x * s); r[5] = (bf16_t)(b.y * s); r[6] = (bf16_t)(b.z * s); r[7] = (bf16_t)(b.w * s);
  return r;
}

// bf16 constants, converted once per launch (same data every call)
__device__ ushort g_wb[NOC * NC];          // [Wq*scale ; Wkv] bf16
__device__ ushort g_pb[HEADS * 64 * NPOS]; // pos_bias bf16

// ===========================================================================
// k_wcast2: weights (Wq scaled by 1/sqrt(32)) + pos_bias -> bf16 globals.
// blocks 0..95: weights (2048 elems each). blocks 96..144: pbias.
// ===========================================================================
__global__ __launch_bounds__(256) void k_wcast2(const float* __restrict__ wq,
                                                const float* __restrict__ wkv,
                                                const float* __restrict__ pb) {
  const float scale = 0.17677669529663687f;  // 1/sqrt(32)
  if (blockIdx.x < 96) {
    int idx = (blockIdx.x * 256 + threadIdx.x) * 8;
    int oc = idx >> 8, c = idx & 255;
    Frag v;
    if (oc < 256) v.b8 = load_bf8s(wq + (size_t)oc * NC + c, scale);
    else          v.b8 = load_bf8(wkv + (size_t)(oc - 256) * NC + c);
    *reinterpret_cast<uint4*>(g_wb + idx) = v.u4;
  } else {
    int idx = ((blockIdx.x - 96) * 256 + threadIdx.x) * 8;  // < 100352
    Frag v;
    v.b8 = load_bf8(pb + idx);
    *reinterpret_cast<uint4*>(g_pb + idx) = v.u4;
  }
}

// ===========================================================================
// k_projF: fused transpose + GEMM. qkv[row][oc] = sum_c x[row(c-major)] * wb.
// Tile: 64 rows x 768 oc (ALL oc -> x read exactly once). 4 waves n-split
// 192 oc each; acc 4x12 f32x4 (192 VGPR). Transpose-in-staging with b32
// pair-packed stores + XOR swizzle. Chunked LDS epilogue, coalesced stores.
// ===========================================================================
__global__ __launch_bounds__(256, 2) void k_projF(const float* __restrict__ x,
                                                  ushort* __restrict__ qkv) {
  __shared__ __align__(16) ushort As[64][264];
  const int row0 = blockIdx.x * 64;     // global row = b*NP + p
  const int b = row0 >> 12;             // /NP
  const int p0 = row0 & (NP - 1);
  const int tid = threadIdx.x, lane = tid & 63, wid = tid >> 6;
  const int quad = lane >> 4, lc = lane & 15;

  // stage: As[p][c ^ ((p>>2&3)<<3)] <- bf16(x[b][c][p0+p]), pair-packed b32
  #pragma unroll
  for (int it = 0; it < 8; ++it) {
    int i = it * 256 + tid;             // 0..2047
    int c = (i >> 4) * 2;               // even, 0..254
    int p4 = (i & 15) * 4;
    const float* src = x + ((size_t)(b * NC + c)) * NP + p0 + p4;
    float4 v0 = *reinterpret_cast<const float4*>(src);
    float4 v1 = *reinterpret_cast<const float4*>(src + NP);
    float a0[4] = {v0.x, v0.y, v0.z, v0.w};
    float a1[4] = {v1.x, v1.y, v1.z, v1.w};
    #pragma unroll
    for (int j = 0; j < 4; ++j) {
      int p = p4 + j;
      int cc = c ^ (((p >> 2) & 3) << 3);   // xor bits 3,4: evenness kept
      uint32_t pk = (uint32_t)f2bf(a0[j]) | ((uint32_t)f2bf(a1[j]) << 16);
      *reinterpret_cast<uint32_t*>(&As[p][cc]) = pk;
    }
  }
  __syncthreads();

  const int n0w = wid * 192;
  const int swz = ((lc >> 2) & 3) << 3;
  f32x4 acc[4][12] = {};
  #pragma unroll
  for (int ks = 0; ks < 8; ++ks) {
    const int k0 = ks * 32 + quad * 8;
    Frag a[4];
    #pragma unroll
    for (int mt = 0; mt < 4; ++mt)
      a[mt].u4 = *reinterpret_cast<const uint4*>(&As[mt * 16 + lc][k0 ^ swz]);
    #pragma unroll
    for (int nn = 0; nn < 12; ++nn) {
      Frag bb;
      bb.u4 = *reinterpret_cast<const uint4*>(g_wb + (size_t)(n0w + nn * 16 + lc) * NC + k0);
      #pragma unroll
      for (int mt = 0; mt < 4; ++mt)
        acc[mt][nn] = __builtin_amdgcn_mfma_f32_16x16x32_bf16(a[mt].b8, bb.b8, acc[mt][nn], 0, 0, 0);
    }
  }

  // epilogue: 3 chunks of 256 oc through As, then coalesced uint4 stores
  #pragma unroll
  for (int ch = 0; ch < 3; ++ch) {
    __syncthreads();
    #pragma unroll
    for (int nn = 0; nn < 12; ++nn) {
      int oc = n0w + nn * 16 + lc;
      if ((oc >> 8) == ch) {             // wave-uniform per nn
        int col = oc & 255;
        #pragma unroll
        for (int mt = 0; mt < 4; ++mt)
          #pragma unroll
          for (int r = 0; r < 4; ++r)
            As[mt * 16 + quad * 4 + r][col] = f2bf(acc[mt][nn][r]);
      }
    }
    __syncthreads();
    #pragma unroll
    for (int it = 0; it < 8; ++it) {
      int i = it * 256 + tid;
      int r = i >> 5, cs = (i & 31) * 8;
      uint4 u = *reinterpret_cast<const uint4*>(&As[r][cs]);
      *reinterpret_cast<uint4*>(qkv + ((size_t)(row0 + r)) * NOC + ch * 256 + cs) = u;
    }
  }
}

// ===========================================================================
// k_attn_f3: one wg per (b, block, head); 4 waves x 16 queries. LDS 36 KB.
// Scale pre-folded into Wq; bias bf16 from g_pb. osh overlays ksh.
// ===========================================================================
__global__ __launch_bounds__(256) void k_attn_f3(const ushort* __restrict__ qkv,
                                                 float* __restrict__ out) {
  __shared__ __align__(16) ushort ksh[NPAD][40];    // 17920 B; osh overlays
  __shared__ __align__(16) ushort vth[32][232];     // [d][key^swz]
  __shared__ __align__(16) ushort psh[4][16][32];   // per-wave P slab
  float (*osh)[33] = reinterpret_cast<float(*)[33]>(&ksh[0][0]);  // 8448 B
  const int b = blockIdx.z, h = blockIdx.y, blk = blockIdx.x;
  const int by = blk >> 3, bx = blk & 7;
  const int tid = threadIdx.x, lane = tid & 63, w = tid >> 6;
  const int quad = lane >> 4, lc = lane & 15;

  // q A-fragment straight from qkv: A[m=lc][k=quad*8+j]
  Frag aq;
  {
    int q = w * 16 + lc;
    int py = by * 8 + (q >> 3), px = bx * 8 + (q & 7);
    aq.u4 = *reinterpret_cast<const uint4*>(
        qkv + ((size_t)(b * NP + py * NW + px)) * NOC + h * 32 + quad * 8);
  }

  // stage KV window: 224 pos x 8 segs; segs 0..3 -> k, 4..7 -> v^T (swizzled)
  for (int it = 0; it < 7; ++it) {
    int i = it * 256 + tid;
    int pos = i >> 3, seg = i & 7;
    Frag v;
    v.u4 = make_uint4(0u, 0u, 0u, 0u);
    if (pos < NPOS) {
      int wy = pos / WIN;
      int wx = pos - wy * WIN;
      int yq = by * 8 - 3 + wy, xx = bx * 8 - 3 + wx;
      if ((unsigned)yq < (unsigned)NH && (unsigned)xx < (unsigned)NW)
        v.u4 = *reinterpret_cast<const uint4*>(
            qkv + ((size_t)(b * NP + yq * NW + xx)) * NOC + 256 + h * 64 + seg * 8);
    }
    if (seg < 4) {
      *reinterpret_cast<uint4*>(&ksh[pos][seg * 8]) = v.u4;
    } else {
      int d0 = (seg - 4) * 8;
      int cp = pos ^ ((seg - 4) << 3);   // XOR swizzle on key index
      #pragma unroll
      for (int j = 0; j < 8; ++j) vth[d0 + j][cp] = v.us[j];
    }
  }
  __syncthreads();

  // S = q k^T : 14 n-tiles of 16 keys (scale already folded into q)
  f32x4 s[14];
  #pragma unroll
  for (int nt = 0; nt < 14; ++nt) {
    Frag bk;
    bk.u4 = *reinterpret_cast<const uint4*>(&ksh[nt * 16 + lc][quad * 8]);
    f32x4 z = {0.f, 0.f, 0.f, 0.f};
    s[nt] = __builtin_amdgcn_mfma_f32_16x16x32_bf16(aq.b8, bk.b8, z, 0, 0, 0);
  }

  const int qi = w * 16 + quad * 4;          // C-layout row = quad*4 + r
  float lsum[4] = {0.f, 0.f, 0.f, 0.f};
  #pragma unroll
  for (int nt = 0; nt < 14; ++nt) {
    int col = nt * 16 + lc;
    #pragma unroll
    for (int r = 0; r < 4; ++r) {
      float p = 0.f;
      if (col < NPOS)
        p = __expf(s[nt][r] + bf2f(g_pb[(h * 64 + qi + r) * NPOS + col]));
      s[nt][r] = p;
      lsum[r] += p;
    }
  }

  // O = P V : 7 slabs of 32 keys, P round-tripped per slab (wave-private)
  f32x4 o[2] = {};
  #pragma unroll
  for (int kt = 0; kt < 7; ++kt) {
    #pragma unroll
    for (int t = 0; t < 2; ++t)
      #pragma unroll
      for (int r = 0; r < 4; ++r)
        psh[w][quad * 4 + r][t * 16 + lc] = f2bf(s[2 * kt + t][r]);
    Frag ap;
    ap.u4 = *reinterpret_cast<const uint4*>(&psh[w][lc][quad * 8]);
    #pragma unroll
    for (int t = 0; t < 2; ++t) {
      int d = t * 16 + lc;
      int g = (kt * 4 + quad) ^ ((d >> 3) & 3);
      Frag bv;
      bv.u4 = *reinterpret_cast<const uint4*>(&vth[d][g * 8]);
      o[t] = __builtin_amdgcn_mfma_f32_16x16x32_bf16(ap.b8, bv.b8, o[t], 0, 0, 0);
    }
  }

  #pragma unroll
  for (int m = 1; m < 16; m <<= 1)
    #pragma unroll
    for (int r = 0; r < 4; ++r) lsum[r] += __shfl_xor(lsum[r], m);
  float rinv[4];
  #pragma unroll
  for (int r = 0; r < 4; ++r) rinv[r] = 1.0f / lsum[r];

  __syncthreads();   // all waves done with ksh before osh overlay write
  #pragma unroll
  for (int t = 0; t < 2; ++t)
    #pragma unroll
    for (int r = 0; r < 4; ++r)
      osh[w * 16 + quad * 4 + r][t * 16 + lc] = o[t][r] * rinv[r];
  __syncthreads();

  // write: out[b][h*32+d][by*8+yy][bx*8..+8], f32, two float4 per lane
  {
    int d = tid >> 3, yy = tid & 7;
    float4 o0, o1;
    o0.x = osh[yy * 8 + 0][d]; o0.y = osh[yy * 8 + 1][d];
    o0.z = osh[yy * 8 + 2][d]; o0.w = osh[yy * 8 + 3][d];
    o1.x = osh[yy * 8 + 4][d]; o1.y = osh[yy * 8 + 5][d];
    o1.z = osh[yy * 8 + 6][d]; o1.w = osh[yy * 8 + 7][d];
    float* op = out + ((size_t)(b * NC + h * 32 + d) * NH + by * 8 + yy) * NW + bx * 8;
    *reinterpret_cast<float4*>(op) = o0;
    *reinterpret_cast<float4*>(op + 4) = o1;
  }
}

// ===========================================================================
// LOW FALLBACK (ws < 96 MiB): Round-3 kernels, proven correct
// ===========================================================================
__global__ __launch_bounds__(256) void k_kv(const float* __restrict__ x,
                                            const float* __restrict__ wkv,
                                            ushort* __restrict__ kvb) {
  __shared__ __align__(16) ushort As[64][264];
  const int b = blockIdx.z;
  const int y = blockIdx.x;
  const int n0 = blockIdx.y * 128;
  const int tid = threadIdx.x;
  const int lane = tid & 63, wid = tid >> 6;
  const int quad = lane >> 4, lc = lane & 15;
  #pragma unroll
  for (int it = 0; it < 16; ++it) {
    int i = it * 256 + tid;
    int c = i >> 4, xs = (i & 15) * 4;
    float4 v = *reinterpret_cast<const float4*>(x + ((size_t)(b * NC + c)) * NP + y * NW + xs);
    As[xs + 0][c] = f2bf(v.x);
    As[xs + 1][c] = f2bf(v.y);
    As[xs + 2][c] = f2bf(v.z);
    As[xs + 3][c] = f2bf(v.w);
  }
  __syncthreads();
  const int wm = (wid & 1) * 32, wn = (wid >> 1) * 64;
  f32x4 acc[2][4] = {};
  #pragma unroll
  for (int ks = 0; ks < 8; ++ks) {
    const int k0 = ks * 32 + quad * 8;
    Frag a[2];
    bf16x8 bb[4];
    #pragma unroll
    for (int mt = 0; mt < 2; ++mt)
      a[mt].u4 = *reinterpret_cast<const uint4*>(&As[wm + mt * 16 + lc][k0]);
    #pragma unroll
    for (int nt = 0; nt < 4; ++nt) {
      int oc = n0 + wn + nt * 16 + lc;
      bb[nt] = load_bf8(wkv + (size_t)oc * NC + k0);
    }
    #pragma unroll
    for (int mt = 0; mt < 2; ++mt)
      #pragma unroll
      for (int nt = 0; nt < 4; ++nt)
        acc[mt][nt] = __builtin_amdgcn_mfma_f32_16x16x32_bf16(a[mt].b8, bb[nt], acc[mt][nt], 0, 0, 0);
  }
  #pragma unroll
  for (int mt = 0; mt < 2; ++mt) {
    #pragma unroll
    for (int r = 0; r < 4; ++r) {
      int pl = wm + mt * 16 + quad * 4 + r;
      #pragma unroll
      for (int nt = 0; nt < 4; ++nt) {
        int oc = n0 + wn + nt * 16 + lc;
        kvb[((size_t)(b * NP + y * NW + pl)) * NKV + oc] = f2bf(acc[mt][nt][r]);
      }
    }
  }
}

__global__ __launch_bounds__(256) void k_attn_v3(const float* __restrict__ x,
                                                 const float* __restrict__ wq,
                                                 const ushort* __restrict__ kvb,
                                                 const float* __restrict__ pbias,
                                                 float* __restrict__ out) {
  __shared__ __align__(16) ushort ksh[NPAD][40];
  __shared__ __align__(16) ushort vth[32][232];
  __shared__ __align__(16) ushort psh[4][16][232];
  __shared__ __align__(16) ushort qsh[4][16][32];
  __shared__ __align__(16) float osh[64][33];
  const int b = blockIdx.z, h = blockIdx.y, blk = blockIdx.x;
  const int by = blk >> 3, bx = blk & 7;
  const int tid = threadIdx.x, lane = tid & 63, w = tid >> 6;
  const int quad = lane >> 4, lc = lane & 15;

  for (int it = 0; it < 7; ++it) {
    int i = it * 256 + tid;
    int pos = i >> 3, seg = i & 7;
    Frag v;
    v.u4 = make_uint4(0u, 0u, 0u, 0u);
    if (pos < NPOS) {
      int wy = pos / WIN;
      int wx = pos - wy * WIN;
      int yq = by * 8 - 3 + wy, xx = bx * 8 - 3 + wx;
      if ((unsigned)yq < (unsigned)NH && (unsigned)xx < (unsigned)NW)
        v.u4 = *reinterpret_cast<const uint4*>(
            kvb + ((size_t)(b * NP + yq * NW + xx)) * NKV + h * 64 + seg * 8);
    }
    if (seg < 4) {
      *reinterpret_cast<uint4*>(&ksh[pos][seg * 8]) = v.u4;
    } else {
      int d0 = (seg - 4) * 8;
      #pragma unroll
      for (int j = 0; j < 8; ++j) vth[d0 + j][pos] = v.us[j];
    }
  }

  f32x4 qacc[2] = {};
  {
    const int q = w * 16 + lc;
    const size_t p = (size_t)(by * 8 + (q >> 3)) * NW + bx * 8 + (q & 7);
    #pragma unroll
    for (int ks = 0; ks < 8; ++ks) {
      const int k0 = ks * 32 + quad * 8;
      Frag ax;
      #pragma unroll
      for (int j = 0; j < 8; ++j)
        ax.us[j] = f2bf(x[((size_t)(b * NC + k0 + j)) * NP + p]);
      bf16x8 bw0 = load_bf8(wq + (size_t)(h * 32 + lc) * NC + k0);
      bf16x8 bw1 = load_bf8(wq + (size_t)(h * 32 + 16 + lc) * NC + k0);
      qacc[0] = __builtin_amdgcn_mfma_f32_16x16x32_bf16(ax.b8, bw0, qacc[0], 0, 0, 0);
      qacc[1] = __builtin_amdgcn_mfma_f32_16x16x32_bf16(ax.b8, bw1, qacc[1], 0, 0, 0);
    }
  }
  #pragma unroll
  for (int t = 0; t < 2; ++t)
    #pragma unroll
    for (int r = 0; r < 4; ++r)
      qsh[w][quad * 4 + r][t * 16 + lc] = f2bf(qacc[t][r]);
  Frag aq;
  aq.u4 = *reinterpret_cast<const uint4*>(&qsh[w][lc][quad * 8]);

  __syncthreads();

  f32x4 s[14];
  #pragma unroll
  for (int nt = 0; nt < 14; ++nt) {
    Frag bk;
    bk.u4 = *reinterpret_cast<const uint4*>(&ksh[nt * 16 + lc][quad * 8]);
    f32x4 z = {0.f, 0.f, 0.f, 0.f};
    s[nt] = __builtin_amdgcn_mfma_f32_16x16x32_bf16(aq.b8, bk.b8, z, 0, 0, 0);
  }

  const float scale = 0.17677669529663687f;
  const int qi = w * 16 + quad * 4;
  float lsum[4] = {0.f, 0.f, 0.f, 0.f};
  #pragma unroll
  for (int nt = 0; nt < 14; ++nt) {
    int col = nt * 16 + lc;
    #pragma unroll
    for (int r = 0; r < 4; ++r) {
      float p = 0.f;
      if (col < NPOS)
        p = __expf(s[nt][r] * scale + pbias[(size_t)(h * 64 + qi + r) * NPOS + col]);
      s[nt][r] = p;
      lsum[r] += p;
    }
  }
  #pragma unroll
  for (int m = 1; m < 16; m <<= 1) {
    #pragma unroll
    for (int r = 0; r < 4; ++r) lsum[r] += __shfl_xor(lsum[r], m);
  }
  #pragma unroll
  for (int nt = 0; nt < 14; ++nt) {
    #pragma unroll
    for (int r = 0; r < 4; ++r) psh[w][quad * 4 + r][nt * 16 + lc] = f2bf(s[nt][r]);
  }
  f32x4 o[2] = {};
  #pragma unroll
  for (int kt = 0; kt < 7; ++kt) {
    Frag ap;
    ap.u4 = *reinterpret_cast<const uint4*>(&psh[w][lc][kt * 32 + quad * 8]);
    #pragma unroll
    for (int t = 0; t < 2; ++t) {
      Frag bv;
      bv.u4 = *reinterpret_cast<const uint4*>(&vth[t * 16 + lc][kt * 32 + quad * 8]);
      o[t] = __builtin_amdgcn_mfma_f32_16x16x32_bf16(ap.b8, bv.b8, o[t], 0, 0, 0);
    }
  }
  #pragma unroll
  for (int t = 0; t < 2; ++t)
    #pragma unroll
    for (int r = 0; r < 4; ++r)
      osh[w * 16 + quad * 4 + r][t * 16 + lc] = o[t][r] / lsum[r];
  __syncthreads();
  {
    int d = tid >> 3, yy = tid & 7;
    float4 o0, o1;
    o0.x = osh[yy * 8 + 0][d]; o0.y = osh[yy * 8 + 1][d];
    o0.z = osh[yy * 8 + 2][d]; o0.w = osh[yy * 8 + 3][d];
    o1.x = osh[yy * 8 + 4][d]; o1.y = osh[yy * 8 + 5][d];
    o1.z = osh[yy * 8 + 6][d]; o1.w = osh[yy * 8 + 7][d];
    float* op = out + ((size_t)(b * NC + h * 32 + d) * NH + by * 8 + yy) * NW + bx * 8;
    *reinterpret_cast<float4*>(op) = o0;
    *reinterpret_cast<float4*>(op + 4) = o1;
  }
}

// ---------------------------------------------------------------------------
extern "C" void kernel_launch(void* const* d_in, const int* in_sizes, int n_in,
                              void* d_out, int out_size, void* d_ws, size_t ws_size,
                              hipStream_t stream) {
  const float* x   = (const float*)d_in[0];  // (16,256,64,64) f32
  const float* wq  = (const float*)d_in[1];  // (256,256) f32
  const float* wkv = (const float*)d_in[2];  // (512,256) f32
  const float* pb  = (const float*)d_in[3];  // (8,64,196) f32
  float* outp = (float*)d_out;               // (16,256,64,64) f32

  const size_t qkv_bytes = (size_t)NB * NP * NOC * sizeof(ushort);  // 96 MiB

  if (ws_size >= qkv_bytes) {
    ushort* qkv = (ushort*)d_ws;
    k_wcast2<<<dim3(96 + 49), 256, 0, stream>>>(wq, wkv, pb);
    k_projF<<<dim3(NB * NP / 64), 256, 0, stream>>>(x, qkv);
    k_attn_f3<<<dim3(64, HEADS, NB), 256, 0, stream>>>(qkv, outp);
  } else {
    ushort* kvb = (ushort*)d_ws;               // 64 MiB
    k_kv<<<dim3(NH, NKV / 128, NB), 256, 0, stream>>>(x, wkv, kvb);
    k_attn_v3<<<dim3(64, HEADS, NB), 256, 0, stream>>>(x, wq, kvb, pb, outp);
  }
}

// Round 7
// 298.464 us; speedup vs baseline: 1.0381x; 1.0381x over previous
//
#include <hip/hip_runtime.h>
#include <hip/hip_bf16.h>
#include <stdint.h>

// Problem constants (B,C,H,W)=(16,256,64,64), HEADS=8, BS=8, HALO=3
// Inputs f32; MFMA math bf16, f32 accumulate; output f32.
#define HEADS 8
#define WIN 14
#define NPOS 196          // WIN*WIN
#define NPAD 224          // padded key count = 7*32
#define NB 16
#define NC 256
#define NH 64
#define NW 64
#define NP 4096           // NH*NW
#define NKV 512           // kv channels (fallback layout)
#define NOC 768           // q(256) + kv(512) channels

typedef __bf16 bf16_t;
typedef bf16_t bf16x8 __attribute__((ext_vector_type(8)));
typedef float f32x4 __attribute__((ext_vector_type(4)));

union Frag {
  uint4 u4;
  bf16x8 b8;
  ushort us[8];
};

__device__ __forceinline__ ushort f2bf(float f) {
  bf16_t h = (bf16_t)f;
  return __builtin_bit_cast(ushort, h);
}
__device__ __forceinline__ float bf2f(ushort u) {
  uint32_t t = ((uint32_t)u) << 16;
  return __builtin_bit_cast(float, t);
}
__device__ __forceinline__ bf16x8 load_bf8(const float* __restrict__ p) {
  float4 a = *reinterpret_cast<const float4*>(p);
  float4 b = *reinterpret_cast<const float4*>(p + 4);
  bf16x8 r;
  r[0] = (bf16_t)a.x; r[1] = (bf16_t)a.y; r[2] = (bf16_t)a.z; r[3] = (bf16_t)a.w;
  r[4] = (bf16_t)b.x; r[5] = (bf16_t)b.y; r[6] = (bf16_t)b.z; r[7] = (bf16_t)b.w;
  return r;
}
__device__ __forceinline__ bf16x8 load_bf8s(const float* __restrict__ p, float s) {
  float4 a = *reinterpret_cast<const float4*>(p);
  float4 b = *reinterpret_cast<const float4*>(p + 4);
  bf16x8 r;
  r[0] = (bf16_t)(a.x * s); r[1] = (bf16_t)(a.y * s); r[2] = (bf16_t)(a.z * s); r[3] = (bf16_t)(a.w * s);
  r[4] = (bf16_t)(b.x * s); r[5] = (bf16_t)(b.y * s); r[6] = (bf16_t)(b.z * s); r[7] = (bf16_t)(b.w * s);
  return r;
}

// ===========================================================================
// k_wcast3: [Wq*scale ; Wkv] f32 -> wb bf16 (ws tail); pos_bias -> pbb bf16.
// blocks 0..95: weights. blocks 96..144: pbias.
// ===========================================================================
__global__ __launch_bounds__(256) void k_wcast3(const float* __restrict__ wq,
                                                const float* __restrict__ wkv,
                                                const float* __restrict__ pb,
                                                ushort* __restrict__ wb,
                                                ushort* __restrict__ pbb) {
  const float scale = 0.17677669529663687f;  // 1/sqrt(32)
  if (blockIdx.x < 96) {
    int idx = (blockIdx.x * 256 + threadIdx.x) * 8;
    int oc = idx >> 8, c = idx & 255;
    Frag v;
    if (oc < 256) v.b8 = load_bf8s(wq + (size_t)oc * NC + c, scale);
    else          v.b8 = load_bf8(wkv + (size_t)(oc - 256) * NC + c);
    *reinterpret_cast<uint4*>(wb + idx) = v.u4;
  } else {
    int idx = ((blockIdx.x - 96) * 256 + threadIdx.x) * 8;  // < 100352
    Frag v;
    v.b8 = load_bf8(pb + idx);
    *reinterpret_cast<uint4*>(pbb + idx) = v.u4;
  }
}

// ===========================================================================
// k_projF: fused transpose + GEMM. qkv[row][oc] = sum_c x[row(c-major)] * wb.
// Tile: 64 rows x 768 oc (x read exactly once). 4 waves n-split 192 oc each;
// acc 4x12 f32x4 (192 VGPR) -> launch_bounds(256,1): NO spill (R6 lesson:
// (256,2) capped VGPR at 128 and spilled ~90 regs/thread -> +91 MB writes).
// ===========================================================================
__global__ __launch_bounds__(256, 1) void k_projF(const float* __restrict__ x,
                                                  const ushort* __restrict__ wb,
                                                  ushort* __restrict__ qkv) {
  __shared__ __align__(16) ushort As[64][264];
  const int row0 = blockIdx.x * 64;     // global row = b*NP + p
  const int b = row0 >> 12;             // /NP
  const int p0 = row0 & (NP - 1);
  const int tid = threadIdx.x, lane = tid & 63, wid = tid >> 6;
  const int quad = lane >> 4, lc = lane & 15;

  // stage: As[p][c ^ ((p>>2&3)<<3)] <- bf16(x[b][c][p0+p]), pair-packed b32
  #pragma unroll
  for (int it = 0; it < 8; ++it) {
    int i = it * 256 + tid;             // 0..2047
    int c = (i >> 4) * 2;               // even, 0..254
    int p4 = (i & 15) * 4;
    const float* src = x + ((size_t)(b * NC + c)) * NP + p0 + p4;
    float4 v0 = *reinterpret_cast<const float4*>(src);
    float4 v1 = *reinterpret_cast<const float4*>(src + NP);
    float a0[4] = {v0.x, v0.y, v0.z, v0.w};
    float a1[4] = {v1.x, v1.y, v1.z, v1.w};
    #pragma unroll
    for (int j = 0; j < 4; ++j) {
      int p = p4 + j;
      int cc = c ^ (((p >> 2) & 3) << 3);   // xor bits 3,4: evenness kept
      uint32_t pk = (uint32_t)f2bf(a0[j]) | ((uint32_t)f2bf(a1[j]) << 16);
      *reinterpret_cast<uint32_t*>(&As[p][cc]) = pk;
    }
  }
  __syncthreads();

  const int n0w = wid * 192;
  const int swz = ((lc >> 2) & 3) << 3;
  f32x4 acc[4][12] = {};
  #pragma unroll
  for (int ks = 0; ks < 8; ++ks) {
    const int k0 = ks * 32 + quad * 8;
    Frag a[4];
    #pragma unroll
    for (int mt = 0; mt < 4; ++mt)
      a[mt].u4 = *reinterpret_cast<const uint4*>(&As[mt * 16 + lc][k0 ^ swz]);
    #pragma unroll
    for (int nn = 0; nn < 12; ++nn) {
      Frag bb;
      bb.u4 = *reinterpret_cast<const uint4*>(wb + (size_t)(n0w + nn * 16 + lc) * NC + k0);
      #pragma unroll
      for (int mt = 0; mt < 4; ++mt)
        acc[mt][nn] = __builtin_amdgcn_mfma_f32_16x16x32_bf16(a[mt].b8, bb.b8, acc[mt][nn], 0, 0, 0);
    }
  }

  // epilogue: 3 chunks of 256 oc through As, then coalesced uint4 stores
  #pragma unroll
  for (int ch = 0; ch < 3; ++ch) {
    __syncthreads();
    #pragma unroll
    for (int nn = 0; nn < 12; ++nn) {
      int oc = n0w + nn * 16 + lc;
      if ((oc >> 8) == ch) {             // wave-uniform per nn
        int col = oc & 255;
        #pragma unroll
        for (int mt = 0; mt < 4; ++mt)
          #pragma unroll
          for (int r = 0; r < 4; ++r)
            As[mt * 16 + quad * 4 + r][col] = f2bf(acc[mt][nn][r]);
      }
    }
    __syncthreads();
    #pragma unroll
    for (int it = 0; it < 8; ++it) {
      int i = it * 256 + tid;
      int r = i >> 5, cs = (i & 31) * 8;
      uint4 u = *reinterpret_cast<const uint4*>(&As[r][cs]);
      *reinterpret_cast<uint4*>(qkv + ((size_t)(row0 + r)) * NOC + ch * 256 + cs) = u;
    }
  }
}

// ===========================================================================
// k_attn_f4: proven R5 f2 structure; scale pre-folded into Wq, bias bf16.
// One wg per (b, block, head); 4 waves x 16 queries. LDS 36 KB, osh overlay.
// ===========================================================================
__global__ __launch_bounds__(256) void k_attn_f4(const ushort* __restrict__ qkv,
                                                 const ushort* __restrict__ pbb,
                                                 float* __restrict__ out) {
  __shared__ __align__(16) ushort ksh[NPAD][40];    // 17920 B; osh overlays
  __shared__ __align__(16) ushort vth[32][232];     // [d][key^swz]
  __shared__ __align__(16) ushort psh[4][16][32];   // per-wave P slab
  float (*osh)[33] = reinterpret_cast<float(*)[33]>(&ksh[0][0]);  // 8448 B
  const int b = blockIdx.z, h = blockIdx.y, blk = blockIdx.x;
  const int by = blk >> 3, bx = blk & 7;
  const int tid = threadIdx.x, lane = tid & 63, w = tid >> 6;
  const int quad = lane >> 4, lc = lane & 15;

  // q A-fragment straight from qkv: A[m=lc][k=quad*8+j]
  Frag aq;
  {
    int q = w * 16 + lc;
    int py = by * 8 + (q >> 3), px = bx * 8 + (q & 7);
    aq.u4 = *reinterpret_cast<const uint4*>(
        qkv + ((size_t)(b * NP + py * NW + px)) * NOC + h * 32 + quad * 8);
  }

  // stage KV window: 224 pos x 8 segs; segs 0..3 -> k, 4..7 -> v^T (swizzled)
  for (int it = 0; it < 7; ++it) {
    int i = it * 256 + tid;
    int pos = i >> 3, seg = i & 7;
    Frag v;
    v.u4 = make_uint4(0u, 0u, 0u, 0u);
    if (pos < NPOS) {
      int wy = pos / WIN;
      int wx = pos - wy * WIN;
      int yq = by * 8 - 3 + wy, xx = bx * 8 - 3 + wx;
      if ((unsigned)yq < (unsigned)NH && (unsigned)xx < (unsigned)NW)
        v.u4 = *reinterpret_cast<const uint4*>(
            qkv + ((size_t)(b * NP + yq * NW + xx)) * NOC + 256 + h * 64 + seg * 8);
    }
    if (seg < 4) {
      *reinterpret_cast<uint4*>(&ksh[pos][seg * 8]) = v.u4;
    } else {
      int d0 = (seg - 4) * 8;
      int cp = pos ^ ((seg - 4) << 3);   // XOR swizzle on key index
      #pragma unroll
      for (int j = 0; j < 8; ++j) vth[d0 + j][cp] = v.us[j];
    }
  }
  __syncthreads();

  // S = q k^T : 14 n-tiles of 16 keys (scale already folded into q)
  f32x4 s[14];
  #pragma unroll
  for (int nt = 0; nt < 14; ++nt) {
    Frag bk;
    bk.u4 = *reinterpret_cast<const uint4*>(&ksh[nt * 16 + lc][quad * 8]);
    f32x4 z = {0.f, 0.f, 0.f, 0.f};
    s[nt] = __builtin_amdgcn_mfma_f32_16x16x32_bf16(aq.b8, bk.b8, z, 0, 0, 0);
  }

  const int qi = w * 16 + quad * 4;          // C-layout row = quad*4 + r
  float lsum[4] = {0.f, 0.f, 0.f, 0.f};
  #pragma unroll
  for (int nt = 0; nt < 14; ++nt) {
    int col = nt * 16 + lc;
    #pragma unroll
    for (int r = 0; r < 4; ++r) {
      float p = 0.f;
      if (col < NPOS)
        p = __expf(s[nt][r] + bf2f(pbb[(h * 64 + qi + r) * NPOS + col]));
      s[nt][r] = p;
      lsum[r] += p;
    }
  }

  // O = P V : 7 slabs of 32 keys, P round-tripped per slab (wave-private)
  f32x4 o[2] = {};
  #pragma unroll
  for (int kt = 0; kt < 7; ++kt) {
    #pragma unroll
    for (int t = 0; t < 2; ++t)
      #pragma unroll
      for (int r = 0; r < 4; ++r)
        psh[w][quad * 4 + r][t * 16 + lc] = f2bf(s[2 * kt + t][r]);
    Frag ap;
    ap.u4 = *reinterpret_cast<const uint4*>(&psh[w][lc][quad * 8]);
    #pragma unroll
    for (int t = 0; t < 2; ++t) {
      int d = t * 16 + lc;
      int g = (kt * 4 + quad) ^ ((d >> 3) & 3);
      Frag bv;
      bv.u4 = *reinterpret_cast<const uint4*>(&vth[d][g * 8]);
      o[t] = __builtin_amdgcn_mfma_f32_16x16x32_bf16(ap.b8, bv.b8, o[t], 0, 0, 0);
    }
  }

  #pragma unroll
  for (int m = 1; m < 16; m <<= 1)
    #pragma unroll
    for (int r = 0; r < 4; ++r) lsum[r] += __shfl_xor(lsum[r], m);
  float rinv[4];
  #pragma unroll
  for (int r = 0; r < 4; ++r) rinv[r] = 1.0f / lsum[r];

  __syncthreads();   // all waves done with ksh before osh overlay write
  #pragma unroll
  for (int t = 0; t < 2; ++t)
    #pragma unroll
    for (int r = 0; r < 4; ++r)
      osh[w * 16 + quad * 4 + r][t * 16 + lc] = o[t][r] * rinv[r];
  __syncthreads();

  // write: out[b][h*32+d][by*8+yy][bx*8..+8], f32, two float4 per lane
  {
    int d = tid >> 3, yy = tid & 7;
    float4 o0, o1;
    o0.x = osh[yy * 8 + 0][d]; o0.y = osh[yy * 8 + 1][d];
    o0.z = osh[yy * 8 + 2][d]; o0.w = osh[yy * 8 + 3][d];
    o1.x = osh[yy * 8 + 4][d]; o1.y = osh[yy * 8 + 5][d];
    o1.z = osh[yy * 8 + 6][d]; o1.w = osh[yy * 8 + 7][d];
    float* op = out + ((size_t)(b * NC + h * 32 + d) * NH + by * 8 + yy) * NW + bx * 8;
    *reinterpret_cast<float4*>(op) = o0;
    *reinterpret_cast<float4*>(op + 4) = o1;
  }
}

// ===========================================================================
// LOW FALLBACK (ws too small): Round-3 kernels, proven correct
// ===========================================================================
__global__ __launch_bounds__(256) void k_kv(const float* __restrict__ x,
                                            const float* __restrict__ wkv,
                                            ushort* __restrict__ kvb) {
  __shared__ __align__(16) ushort As[64][264];
  const int b = blockIdx.z;
  const int y = blockIdx.x;
  const int n0 = blockIdx.y * 128;
  const int tid = threadIdx.x;
  const int lane = tid & 63, wid = tid >> 6;
  const int quad = lane >> 4, lc = lane & 15;
  #pragma unroll
  for (int it = 0; it < 16; ++it) {
    int i = it * 256 + tid;
    int c = i >> 4, xs = (i & 15) * 4;
    float4 v = *reinterpret_cast<const float4*>(x + ((size_t)(b * NC + c)) * NP + y * NW + xs);
    As[xs + 0][c] = f2bf(v.x);
    As[xs + 1][c] = f2bf(v.y);
    As[xs + 2][c] = f2bf(v.z);
    As[xs + 3][c] = f2bf(v.w);
  }
  __syncthreads();
  const int wm = (wid & 1) * 32, wn = (wid >> 1) * 64;
  f32x4 acc[2][4] = {};
  #pragma unroll
  for (int ks = 0; ks < 8; ++ks) {
    const int k0 = ks * 32 + quad * 8;
    Frag a[2];
    bf16x8 bb[4];
    #pragma unroll
    for (int mt = 0; mt < 2; ++mt)
      a[mt].u4 = *reinterpret_cast<const uint4*>(&As[wm + mt * 16 + lc][k0]);
    #pragma unroll
    for (int nt = 0; nt < 4; ++nt) {
      int oc = n0 + wn + nt * 16 + lc;
      bb[nt] = load_bf8(wkv + (size_t)oc * NC + k0);
    }
    #pragma unroll
    for (int mt = 0; mt < 2; ++mt)
      #pragma unroll
      for (int nt = 0; nt < 4; ++nt)
        acc[mt][nt] = __builtin_amdgcn_mfma_f32_16x16x32_bf16(a[mt].b8, bb[nt], acc[mt][nt], 0, 0, 0);
  }
  #pragma unroll
  for (int mt = 0; mt < 2; ++mt) {
    #pragma unroll
    for (int r = 0; r < 4; ++r) {
      int pl = wm + mt * 16 + quad * 4 + r;
      #pragma unroll
      for (int nt = 0; nt < 4; ++nt) {
        int oc = n0 + wn + nt * 16 + lc;
        kvb[((size_t)(b * NP + y * NW + pl)) * NKV + oc] = f2bf(acc[mt][nt][r]);
      }
    }
  }
}

__global__ __launch_bounds__(256) void k_attn_v3(const float* __restrict__ x,
                                                 const float* __restrict__ wq,
                                                 const ushort* __restrict__ kvb,
                                                 const float* __restrict__ pbias,
                                                 float* __restrict__ out) {
  __shared__ __align__(16) ushort ksh[NPAD][40];
  __shared__ __align__(16) ushort vth[32][232];
  __shared__ __align__(16) ushort psh[4][16][232];
  __shared__ __align__(16) ushort qsh[4][16][32];
  __shared__ __align__(16) float osh[64][33];
  const int b = blockIdx.z, h = blockIdx.y, blk = blockIdx.x;
  const int by = blk >> 3, bx = blk & 7;
  const int tid = threadIdx.x, lane = tid & 63, w = tid >> 6;
  const int quad = lane >> 4, lc = lane & 15;

  for (int it = 0; it < 7; ++it) {
    int i = it * 256 + tid;
    int pos = i >> 3, seg = i & 7;
    Frag v;
    v.u4 = make_uint4(0u, 0u, 0u, 0u);
    if (pos < NPOS) {
      int wy = pos / WIN;
      int wx = pos - wy * WIN;
      int yq = by * 8 - 3 + wy, xx = bx * 8 - 3 + wx;
      if ((unsigned)yq < (unsigned)NH && (unsigned)xx < (unsigned)NW)
        v.u4 = *reinterpret_cast<const uint4*>(
            kvb + ((size_t)(b * NP + yq * NW + xx)) * NKV + h * 64 + seg * 8);
    }
    if (seg < 4) {
      *reinterpret_cast<uint4*>(&ksh[pos][seg * 8]) = v.u4;
    } else {
      int d0 = (seg - 4) * 8;
      #pragma unroll
      for (int j = 0; j < 8; ++j) vth[d0 + j][pos] = v.us[j];
    }
  }

  f32x4 qacc[2] = {};
  {
    const int q = w * 16 + lc;
    const size_t p = (size_t)(by * 8 + (q >> 3)) * NW + bx * 8 + (q & 7);
    #pragma unroll
    for (int ks = 0; ks < 8; ++ks) {
      const int k0 = ks * 32 + quad * 8;
      Frag ax;
      #pragma unroll
      for (int j = 0; j < 8; ++j)
        ax.us[j] = f2bf(x[((size_t)(b * NC + k0 + j)) * NP + p]);
      bf16x8 bw0 = load_bf8(wq + (size_t)(h * 32 + lc) * NC + k0);
      bf16x8 bw1 = load_bf8(wq + (size_t)(h * 32 + 16 + lc) * NC + k0);
      qacc[0] = __builtin_amdgcn_mfma_f32_16x16x32_bf16(ax.b8, bw0, qacc[0], 0, 0, 0);
      qacc[1] = __builtin_amdgcn_mfma_f32_16x16x32_bf16(ax.b8, bw1, qacc[1], 0, 0, 0);
    }
  }
  #pragma unroll
  for (int t = 0; t < 2; ++t)
    #pragma unroll
    for (int r = 0; r < 4; ++r)
      qsh[w][quad * 4 + r][t * 16 + lc] = f2bf(qacc[t][r]);
  Frag aq;
  aq.u4 = *reinterpret_cast<const uint4*>(&qsh[w][lc][quad * 8]);

  __syncthreads();

  f32x4 s[14];
  #pragma unroll
  for (int nt = 0; nt < 14; ++nt) {
    Frag bk;
    bk.u4 = *reinterpret_cast<const uint4*>(&ksh[nt * 16 + lc][quad * 8]);
    f32x4 z = {0.f, 0.f, 0.f, 0.f};
    s[nt] = __builtin_amdgcn_mfma_f32_16x16x32_bf16(aq.b8, bk.b8, z, 0, 0, 0);
  }

  const float scale = 0.17677669529663687f;
  const int qi = w * 16 + quad * 4;
  float lsum[4] = {0.f, 0.f, 0.f, 0.f};
  #pragma unroll
  for (int nt = 0; nt < 14; ++nt) {
    int col = nt * 16 + lc;
    #pragma unroll
    for (int r = 0; r < 4; ++r) {
      float p = 0.f;
      if (col < NPOS)
        p = __expf(s[nt][r] * scale + pbias[(size_t)(h * 64 + qi + r) * NPOS + col]);
      s[nt][r] = p;
      lsum[r] += p;
    }
  }
  #pragma unroll
  for (int m = 1; m < 16; m <<= 1) {
    #pragma unroll
    for (int r = 0; r < 4; ++r) lsum[r] += __shfl_xor(lsum[r], m);
  }
  #pragma unroll
  for (int nt = 0; nt < 14; ++nt) {
    #pragma unroll
    for (int r = 0; r < 4; ++r) psh[w][quad * 4 + r][nt * 16 + lc] = f2bf(s[nt][r]);
  }
  f32x4 o[2] = {};
  #pragma unroll
  for (int kt = 0; kt < 7; ++kt) {
    Frag ap;
    ap.u4 = *reinterpret_cast<const uint4*>(&psh[w][lc][kt * 32 + quad * 8]);
    #pragma unroll
    for (int t = 0; t < 2; ++t) {
      Frag bv;
      bv.u4 = *reinterpret_cast<const uint4*>(&vth[t * 16 + lc][kt * 32 + quad * 8]);
      o[t] = __builtin_amdgcn_mfma_f32_16x16x32_bf16(ap.b8, bv.b8, o[t], 0, 0, 0);
    }
  }
  #pragma unroll
  for (int t = 0; t < 2; ++t)
    #pragma unroll
    for (int r = 0; r < 4; ++r)
      osh[w * 16 + quad * 4 + r][t * 16 + lc] = o[t][r] / lsum[r];
  __syncthreads();
  {
    int d = tid >> 3, yy = tid & 7;
    float4 o0, o1;
    o0.x = osh[yy * 8 + 0][d]; o0.y = osh[yy * 8 + 1][d];
    o0.z = osh[yy * 8 + 2][d]; o0.w = osh[yy * 8 + 3][d];
    o1.x = osh[yy * 8 + 4][d]; o1.y = osh[yy * 8 + 5][d];
    o1.z = osh[yy * 8 + 6][d]; o1.w = osh[yy * 8 + 7][d];
    float* op = out + ((size_t)(b * NC + h * 32 + d) * NH + by * 8 + yy) * NW + bx * 8;
    *reinterpret_cast<float4*>(op) = o0;
    *reinterpret_cast<float4*>(op + 4) = o1;
  }
}

// ---------------------------------------------------------------------------
extern "C" void kernel_launch(void* const* d_in, const int* in_sizes, int n_in,
                              void* d_out, int out_size, void* d_ws, size_t ws_size,
                              hipStream_t stream) {
  const float* x   = (const float*)d_in[0];  // (16,256,64,64) f32
  const float* wq  = (const float*)d_in[1];  // (256,256) f32
  const float* wkv = (const float*)d_in[2];  // (512,256) f32
  const float* pb  = (const float*)d_in[3];  // (8,64,196) f32
  float* outp = (float*)d_out;               // (16,256,64,64) f32

  const size_t qkv_elems = (size_t)NB * NP * NOC;            // 48 M ushorts
  const size_t wb_elems  = (size_t)NOC * NC;                 // 196608
  const size_t pbb_elems = (size_t)HEADS * 64 * NPOS;        // 100352
  const size_t need = (qkv_elems + wb_elems + pbb_elems) * sizeof(ushort);

  if (ws_size >= need) {      // ws proven >= 128 MiB in R5; need ~96.6 MiB
    ushort* qkv = (ushort*)d_ws;
    ushort* wb  = qkv + qkv_elems;
    ushort* pbb = wb + wb_elems;
    k_wcast3<<<dim3(96 + 49), 256, 0, stream>>>(wq, wkv, pb, wb, pbb);
    k_projF<<<dim3(NB * NP / 64), 256, 0, stream>>>(x, wb, qkv);
    k_attn_f4<<<dim3(64, HEADS, NB), 256, 0, stream>>>(qkv, pbb, outp);
  } else {
    ushort* kvb = (ushort*)d_ws;               // 64 MiB
    k_kv<<<dim3(NH, NKV / 128, NB), 256, 0, stream>>>(x, wkv, kvb);
    k_attn_v3<<<dim3(64, HEADS, NB), 256, 0, stream>>>(x, wq, kvb, pb, outp);
  }
}